// Round 3
// baseline (116.496 us; speedup 1.0000x reference)
//
#include <hip/hip_runtime.h>

// etp: out[n, coff(l3)+m3, u] = sum_p sum_{m1,m2} cg_p[m1,m2,m3] * Y[n, yoff(l1)+m1]
//                               * H[n, coff(l2)+m2, u] * W[n, p, u]
// N=16384 edges, 16 channels (l=0..3, dims 1,3,5,7), MUL=128.
//
// R2: float2 vectorization, 64 lanes per edge (one wave = one edge), 4 edges
// per 256-thread block. Full live set (h[16]+acc[16] as float2 = 64 VGPR)
// fits in registers -> no mid-stream global reloads (R1's VGPR=84 showed the
// compiler was re-fetching h). B reads are wave-uniform LDS broadcasts.

#define BS 256
#define GSZ 64   // lanes per edge (one wave)
#define EPB 4    // edges per block
#define YD 16
#define HD 2048
#define WD 2944
#define NROW 99  // sum of d3 over paths (B rows, padded to 8 floats each)

// X(p, l1, l2, l3, cg_offset, row_offset)
#define FOR_PATHS(X) \
  X(0, 0,0,0,    0,  0) \
  X(1, 0,1,1,    1,  1) \
  X(2, 0,2,2,   10,  4) \
  X(3, 0,3,3,   35,  9) \
  X(4, 1,0,1,   84, 16) \
  X(5, 1,1,0,   93, 19) \
  X(6, 1,1,2,  102, 20) \
  X(7, 1,2,1,  147, 25) \
  X(8, 1,2,3,  192, 28) \
  X(9, 1,3,2,  297, 35) \
  X(10,2,0,2,  402, 40) \
  X(11,2,1,1,  427, 45) \
  X(12,2,1,3,  472, 48) \
  X(13,2,2,0,  577, 55) \
  X(14,2,2,2,  602, 56) \
  X(15,2,3,1,  727, 61) \
  X(16,2,3,3,  832, 64) \
  X(17,3,0,3, 1077, 71) \
  X(18,3,1,2, 1126, 78) \
  X(19,3,2,1, 1231, 83) \
  X(20,3,2,3, 1336, 86) \
  X(21,3,3,0, 1581, 93) \
  X(22,3,3,2, 1630, 94)

__host__ __device__ constexpr int coff(int l) {
  return l == 0 ? 0 : (l == 1 ? 1 : (l == 2 ? 4 : 9));
}

__global__ __launch_bounds__(BS) void etp_kernel(
    const float* __restrict__ Y, const float* __restrict__ H,
    const float* __restrict__ W, const float* __restrict__ CG,
    float* __restrict__ O) {
  const int g = threadIdx.x >> 6;   // edge within block
  const int l = threadIdx.x & 63;   // lane within wave; owns u = 2l, 2l+1
  const int n = blockIdx.x * EPB + g;

  __shared__ __align__(16) float Bsm[EPB][NROW * 8];  // 12672 B
  __shared__ float ysm[EPB][YD];

  { const int t = threadIdx.x;
    if (t < EPB * YD) {
      const int e = t >> 4, c = t & 15;
      ysm[e][c] = Y[(size_t)(blockIdx.x * EPB + e) * YD + c];
    } }
  __syncthreads();

  // Phase 1: B_p[m3][m2] = sum_a cg_p[a,m2,m3] * y[coff(l1)+a], per edge.
  // d2*d3 <= 49 < 64 lanes -> single step per path.
#define BUILD(P, L1, L2, L3, CGO, RO) { \
    constexpr int d1 = 2*(L1)+1, d2 = 2*(L2)+1, d3 = 2*(L3)+1; \
    if (l < d2 * d3) { \
      const int m3 = l / d2, m2 = l - m3 * d2; \
      float s = 0.f; \
      _Pragma("unroll") \
      for (int a = 0; a < d1; ++a) \
        s += CG[(CGO) + (a * d2 + m2) * d3 + m3] * ysm[g][coff(L1) + a]; \
      Bsm[g][((RO) + m3) * 8 + m2] = s; \
    } }
  FOR_PATHS(BUILD)
#undef BUILD
  __syncthreads();

  // Phase 2: per-lane contraction over 2 u's (float2).
  const float2* __restrict__ Hp = (const float2*)(H + (size_t)n * HD);
  const float2* __restrict__ Wp = (const float2*)(W + (size_t)n * WD);
  float2* __restrict__ Op = (float2*)(O + (size_t)n * HD);

  float2 h[YD];
#pragma unroll
  for (int c = 0; c < YD; ++c) h[c] = Hp[c * GSZ + l];

  float2 acc[YD];
#pragma unroll
  for (int c = 0; c < YD; ++c) acc[c] = make_float2(0.f, 0.f);

#define DOPATH(P, L1, L2, L3, CGO, RO) { \
    constexpr int d2 = 2*(L2)+1, d3 = 2*(L3)+1; \
    const float2 wv = Wp[(P) * GSZ + l]; \
    _Pragma("unroll") \
    for (int m3 = 0; m3 < d3; ++m3) { \
      const float4* row = (const float4*)&Bsm[g][((RO) + m3) * 8]; \
      float br[8]; \
      *(float4*)&br[0] = row[0]; \
      if (d2 > 4) *(float4*)&br[4] = row[1]; \
      float2 s = make_float2(0.f, 0.f); \
      _Pragma("unroll") \
      for (int m2 = 0; m2 < d2; ++m2) { \
        const float b = br[m2]; \
        const float2 hv = h[coff(L2) + m2]; \
        s.x += b * hv.x; s.y += b * hv.y; \
      } \
      float2& A = acc[coff(L3) + m3]; \
      A.x += s.x * wv.x; A.y += s.y * wv.y; \
    } }
  FOR_PATHS(DOPATH)
#undef DOPATH

#pragma unroll
  for (int c = 0; c < YD; ++c) Op[c * GSZ + l] = acc[c];
}

extern "C" void kernel_launch(void* const* d_in, const int* in_sizes, int n_in,
                              void* d_out, int out_size, void* d_ws, size_t ws_size,
                              hipStream_t stream) {
  const float* Y  = (const float*)d_in[0];
  const float* H  = (const float*)d_in[1];
  const float* W  = (const float*)d_in[2];
  const float* CG = (const float*)d_in[3];
  float* O = (float*)d_out;

  const int n_edges = in_sizes[0] / YD;
  etp_kernel<<<n_edges / EPB, BS, 0, stream>>>(Y, H, W, CG, O);
}